// Round 2
// baseline (102.436 us; speedup 1.0000x reference)
//
#include <hip/hip_runtime.h>
#include <math.h>

// Problem constants (from reference setup_inputs)
#define B_   8
#define L_   128
#define H_   768
#define E_   7          // emotion classes
#define NE_  4          // experts
#define HALF_ 776       // H + E + 1
#define D_   1552       // 2*HALF
#define PPB_ 8256       // L*(L+1)/2
#define NROW_ 1024      // B*L
#define EMO_OUT_ 7168   // NROW_*E_  (emotion_pred floats at head of d_out)

// workspace layout (float units)
#define WEFF_OFF 0          // [1552][4][2] = 12416  (d-major: d*8 + e*2 + c)
#define BEFF_OFF 12416      // [4][2] = 8
#define EARG_OFF 12424      // [1024] int (reinterpreted)
#define GLO_OFF  13448      // [1024][4]
#define GHI_OFF  17544      // [1024][4]
#define AA_OFF   21640      // [1024][4][2]
#define BB_OFF   29832      // [1024][4][2]
// total: 38024 floats = 152096 bytes

// ---------------------------------------------------------------------------
// K1: collapse each expert's two linears into W_eff[d][e][c], b_eff[e][c]
//   W_eff[d][e][c] = sum_h W1[e][d][h] * W2[e][h][c]
//   b_eff[e][c]    = b2[e][c] + sum_h b1[e][h] * W2[e][h][c]
// ---------------------------------------------------------------------------
__global__ __launch_bounds__(256)
void k_weff(const float* __restrict__ w1,   // [4][1552][256]
            const float* __restrict__ w2,   // [4][256][2]
            const float* __restrict__ b1,   // [4][256]
            const float* __restrict__ b2,   // [4][2]
            float* __restrict__ ws) {
    int idx = blockIdx.x * 256 + threadIdx.x;
    if (idx < NE_ * D_) {
        int e = idx / D_, d = idx % D_;
        const float* w1row = w1 + ((size_t)e * D_ + d) * 256;
        const float* w2e   = w2 + e * 512;
        float a0 = 0.f, a1 = 0.f;
        #pragma unroll 8
        for (int h = 0; h < 256; ++h) {
            float x = w1row[h];
            a0 += x * w2e[2 * h];
            a1 += x * w2e[2 * h + 1];
        }
        ws[WEFF_OFF + d * 8 + e * 2 + 0] = a0;
        ws[WEFF_OFF + d * 8 + e * 2 + 1] = a1;
    } else if (idx < NE_ * D_ + 8) {
        int j = idx - NE_ * D_;
        int e = j >> 1, c = j & 1;
        const float* w2e = w2 + e * 512;
        float acc = b2[e * 2 + c];
        for (int h = 0; h < 256; ++h) acc += b1[e * 256 + h] * w2e[2 * h + c];
        ws[BEFF_OFF + j] = acc;
    }
}

// ---------------------------------------------------------------------------
// K2: one wave (64 lanes) per utterance row.
//   - emotion_pred[row][0..6] -> d_out, argmax -> ws
//   - 24 projection dots over the 776-dim concat row:
//       G_lo/G_hi (gate logit halves), A/Bv (effective-expert halves)
// ---------------------------------------------------------------------------
__global__ __launch_bounds__(64)
void k_row(const float* __restrict__ utter,   // [1024][768]
           const int*   __restrict__ spk,     // [1024]
           const float* __restrict__ emoW,    // [768][7]
           const float* __restrict__ emoB,    // [7]
           const float* __restrict__ gateW,   // [1552][4]
           float* __restrict__ ws,
           float* __restrict__ out) {
    int row  = blockIdx.x;
    int lane = threadIdx.x;
    const float* x = utter + (size_t)row * H_;

    float aemo[E_];
    float ag[24];   // [0..3]=G_lo  [4..7]=G_hi  [8..15]=A  [16..23]=Bv
    #pragma unroll
    for (int j = 0; j < E_; ++j) aemo[j] = 0.f;
    #pragma unroll
    for (int k = 0; k < 24; ++k) ag[k] = 0.f;

    // single pass over the 768 utterance dims; lane d-stride-64 => coalesced
    for (int d = lane; d < H_; d += 64) {
        float v = x[d];
        const float* ew = emoW + d * E_;
        #pragma unroll
        for (int j = 0; j < E_; ++j) aemo[j] += v * ew[j];
        const float* gl = gateW + d * NE_;
        const float* gh = gateW + (HALF_ + d) * NE_;
        #pragma unroll
        for (int k = 0; k < NE_; ++k) { ag[k] += v * gl[k]; ag[4 + k] += v * gh[k]; }
        const float* wl = ws + WEFF_OFF + d * 8;
        const float* wh = ws + WEFF_OFF + (HALF_ + d) * 8;
        #pragma unroll
        for (int k = 0; k < 8; ++k) { ag[8 + k] += v * wl[k]; ag[16 + k] += v * wh[k]; }
    }

    // reduce emotion sums across the wave (xor butterfly -> every lane has total)
    #pragma unroll
    for (int j = 0; j < E_; ++j) {
        float v = aemo[j];
        for (int o = 32; o > 0; o >>= 1) v += __shfl_xor(v, o, 64);
        aemo[j] = v + emoB[j];
    }

    if (lane == 0) {
        int best = 0; float bv = aemo[0];
        #pragma unroll
        for (int j = 1; j < E_; ++j) if (aemo[j] > bv) { bv = aemo[j]; best = j; }
        ((int*)ws)[EARG_OFF + row] = best;
        #pragma unroll
        for (int j = 0; j < E_; ++j) out[row * E_ + j] = aemo[j];
    }

    // tail dims 768..775 of the concat row: 7 emotion preds + speaker scalar.
    // every lane holds the reduced emotion values, so lanes 0..7 each take one.
    if (lane < 8) {
        float v = (lane < E_) ? aemo[lane] : (float)spk[row];
        int d = H_ + lane;
        const float* gl = gateW + d * NE_;
        const float* gh = gateW + (HALF_ + d) * NE_;
        #pragma unroll
        for (int k = 0; k < NE_; ++k) { ag[k] += v * gl[k]; ag[4 + k] += v * gh[k]; }
        const float* wl = ws + WEFF_OFF + d * 8;
        const float* wh = ws + WEFF_OFF + (HALF_ + d) * 8;
        #pragma unroll
        for (int k = 0; k < 8; ++k) { ag[8 + k] += v * wl[k]; ag[16 + k] += v * wh[k]; }
    }

    // reduce the 24 projection sums
    #pragma unroll
    for (int k = 0; k < 24; ++k) {
        float v = ag[k];
        for (int o = 32; o > 0; o >>= 1) v += __shfl_xor(v, o, 64);
        ag[k] = v;
    }

    if (lane == 0) {
        #pragma unroll
        for (int k = 0; k < NE_; ++k) {
            ws[GLO_OFF + row * 4 + k] = ag[k];
            ws[GHI_OFF + row * 4 + k] = ag[4 + k];
        }
        #pragma unroll
        for (int k = 0; k < 8; ++k) {
            ws[AA_OFF + row * 8 + k] = ag[8 + k];
            ws[BB_OFF + row * 8 + k] = ag[16 + k];
        }
    }
}

// ---------------------------------------------------------------------------
// K3: one block per (b, end); thread t computes pair (t, end) for t <= end.
// ---------------------------------------------------------------------------
__global__ __launch_bounds__(128)
void k_pair(const int* __restrict__ spk,
            const float* __restrict__ ws,
            const float* __restrict__ gate_b,   // [4]
            float* __restrict__ out) {
    int b   = blockIdx.x >> 7;
    int end = blockIdx.x & 127;
    int t   = threadIdx.x;
    if (t > end) return;

    int rt = b * L_ + t;
    int re = b * L_ + end;

    // uniform per-kernel constants (compiler: scalar loads)
    float gb0 = gate_b[0], gb1 = gate_b[1], gb2 = gate_b[2], gb3 = gate_b[3];
    const float* beff = ws + BEFF_OFF;
    float be[8];
    #pragma unroll
    for (int k = 0; k < 8; ++k) be[k] = beff[k];

    const float* glo = ws + GLO_OFF + rt * 4;
    const float* ghi = ws + GHI_OFF + re * 4;
    float lg[NE_];
    lg[0] = glo[0] + ghi[0] + gb0;
    lg[1] = glo[1] + ghi[1] + gb1;
    lg[2] = glo[2] + ghi[2] + gb2;
    lg[3] = glo[3] + ghi[3] + gb3;

    float m = fmaxf(fmaxf(lg[0], lg[1]), fmaxf(lg[2], lg[3]));
    float ex[NE_], s = 0.f;
    #pragma unroll
    for (int k = 0; k < NE_; ++k) { ex[k] = expf(lg[k] - m); s += ex[k]; }
    float inv = 0.4f / s;

    const int* earg = (const int*)ws + EARG_OFF;
    bool seq = (spk[rt] == spk[re]);
    bool eeq = (earg[rt] == earg[re]);
    int lbl = (seq && eeq) ? 0 : (seq ? 1 : (eeq ? 2 : 3));

    const float* A  = ws + AA_OFF + rt * 8;
    const float* Bv = ws + BB_OFF + re * 8;

    float o0 = 0.f, o1 = 0.f;
    #pragma unroll
    for (int e = 0; e < NE_; ++e) {
        float g = ex[e] * inv + ((e == lbl) ? 0.6f : 0.f);
        o0 += g * (A[e * 2 + 0] + Bv[e * 2 + 0] + be[e * 2 + 0]);
        o1 += g * (A[e * 2 + 1] + Bv[e * 2 + 1] + be[e * 2 + 1]);
    }

    int p = ((end * (end + 1)) >> 1) + t;
    float* cp = out + EMO_OUT_ + ((size_t)b * PPB_ + p) * 2;
    cp[0] = o0;
    cp[1] = o1;
}

// ---------------------------------------------------------------------------
extern "C" void kernel_launch(void* const* d_in, const int* in_sizes, int n_in,
                              void* d_out, int out_size, void* d_ws, size_t ws_size,
                              hipStream_t stream) {
    const float* utter = (const float*)d_in[0];  // [8,128,768]
    const int*   spk   = (const int*)  d_in[1];  // [8,128]
    const float* emoW  = (const float*)d_in[2];  // [768,7]
    const float* emoB  = (const float*)d_in[3];  // [7]
    const float* gateW = (const float*)d_in[4];  // [1552,4]
    const float* gateB = (const float*)d_in[5];  // [4]
    const float* w1    = (const float*)d_in[6];  // [4,1552,256]
    const float* b1    = (const float*)d_in[7];  // [4,256]
    const float* w2    = (const float*)d_in[8];  // [4,256,2]
    const float* b2    = (const float*)d_in[9];  // [4,2]

    float* ws  = (float*)d_ws;
    float* out = (float*)d_out;

    // K1: effective expert weights (4*1552 + 8 work items)
    k_weff<<<(NE_ * D_ + 8 + 255) / 256, 256, 0, stream>>>(w1, w2, b1, b2, ws);
    // K2: per-utterance-row projections (one wave per row)
    k_row<<<NROW_, 64, 0, stream>>>(utter, spk, emoW, emoB, gateW, ws, out);
    // K3: per-pair gating + output (one block per (b, end))
    k_pair<<<B_ * L_, 128, 0, stream>>>(spk, ws, gateB, out);
}

// Round 4
// 95.298 us; speedup vs baseline: 1.0749x; 1.0749x over previous
//
#include <hip/hip_runtime.h>
#include <math.h>

// Problem constants (from reference setup_inputs)
#define B_   8
#define L_   128
#define H_   768
#define E_   7          // emotion classes
#define NE_  4          // experts
#define HALF_ 776       // H + E + 1
#define D_   1552       // 2*HALF
#define PPB_ 8256       // L*(L+1)/2
#define NROW_ 1024      // B*L
#define EMO_OUT_ 7168   // NROW_*E_  (emotion_pred floats at head of d_out)

// workspace layout (float units) -- all offsets 16B-aligned
#define WEFF_OFF 0          // [1552][4][2] = 12416  (d-major: d*8 + e*2 + c)
#define BEFF_OFF 12416      // [4][2] = 8
#define EARG_OFF 12424      // [1024] int (reinterpreted)
#define GLO_OFF  13448      // [1024][4]
#define GHI_OFF  17544      // [1024][4]
#define AA_OFF   21640      // [1024][4][2]
#define BB_OFF   29832      // [1024][4][2]

#define WEFF_BLOCKS 97      // 6208 (e,d) pairs / 64 per block

// ---------------------------------------------------------------------------
// K1: collapse each expert's two linears into W_eff[d][e][c], b_eff[e][c].
// 97 blocks x 256 threads: 64 (e,d) pairs per block, 4-way h-split + LDS
// reduce. Block 97 computes b_eff with one wave (8 outputs x 8-lane groups).
// ---------------------------------------------------------------------------
__global__ __launch_bounds__(256)
void k_weff(const float* __restrict__ w1,   // [4][1552][256]
            const float* __restrict__ w2,   // [4][256][2]
            const float* __restrict__ b1,   // [4][256]
            const float* __restrict__ b2,   // [4][2]
            float* __restrict__ ws) {
    int blk = blockIdx.x;
    if (blk < WEFF_BLOCKS) {
        __shared__ float red[4][64][2];
        int dl = threadIdx.x & 63;
        int hc = threadIdx.x >> 6;            // h-chunk 0..3
        int idx = blk * 64 + dl;              // (e,d) flat index, < 6208
        int e = idx / D_, d = idx % D_;
        const float* w1row = w1 + ((size_t)e * D_ + d) * 256 + hc * 64;
        const float* w2e   = w2 + e * 512 + hc * 128;
        float a0 = 0.f, a1 = 0.f;
        #pragma unroll
        for (int h = 0; h < 64; h += 4) {
            float4 wv = *(const float4*)(w1row + h);
            float4 p0 = *(const float4*)(w2e + 2 * h);      // rows h, h+1
            float4 p1 = *(const float4*)(w2e + 2 * h + 4);  // rows h+2, h+3
            a0 += wv.x * p0.x + wv.y * p0.z + wv.z * p1.x + wv.w * p1.z;
            a1 += wv.x * p0.y + wv.y * p0.w + wv.z * p1.y + wv.w * p1.w;
        }
        red[hc][dl][0] = a0;
        red[hc][dl][1] = a1;
        __syncthreads();
        if (hc == 0) {
            float s0 = red[0][dl][0] + red[1][dl][0] + red[2][dl][0] + red[3][dl][0];
            float s1 = red[0][dl][1] + red[1][dl][1] + red[2][dl][1] + red[3][dl][1];
            ws[WEFF_OFF + d * 8 + e * 2 + 0] = s0;
            ws[WEFF_OFF + d * 8 + e * 2 + 1] = s1;
        }
    } else {
        // b_eff[e][c] = b2[e][c] + sum_h b1[e][h] * W2[e][h][c]
        int lane = threadIdx.x;
        if (lane < 64) {
            int j = lane >> 3;                // output 0..7 (e*2+c)
            int part = lane & 7;              // 8-way h split
            int e = j >> 1, c = j & 1;
            const float* w2e = w2 + e * 512;
            const float* b1e = b1 + e * 256;
            float acc = 0.f;
            #pragma unroll 8
            for (int h = part * 32; h < part * 32 + 32; ++h)
                acc += b1e[h] * w2e[2 * h + c];
            acc += __shfl_down(acc, 4, 64);
            acc += __shfl_down(acc, 2, 64);
            acc += __shfl_down(acc, 1, 64);
            if (part == 0) ws[BEFF_OFF + j] = acc + b2[j];
        }
    }
}

// ---------------------------------------------------------------------------
// K2: one wave (64 lanes) per utterance row; each lane owns 4 consecutive d
// per iteration (3 iterations cover 768 dims), all loads float4.
//   - emotion_pred[row][0..6] -> d_out, argmax -> ws
//   - 24 projection dots: G_lo/G_hi (gate halves), A/Bv (eff-expert halves)
// ---------------------------------------------------------------------------
__global__ __launch_bounds__(64)
void k_row(const float* __restrict__ utter,   // [1024][768]
           const int*   __restrict__ spk,     // [1024]
           const float* __restrict__ emoW,    // [768][7]
           const float* __restrict__ emoB,    // [7]
           const float* __restrict__ gateW,   // [1552][4]
           float* __restrict__ ws,
           float* __restrict__ out) {
    int row  = blockIdx.x;
    int lane = threadIdx.x;
    const float* x = utter + (size_t)row * H_;

    float aemo[E_];
    float ag[24];   // [0..3]=G_lo  [4..7]=G_hi  [8..15]=A  [16..23]=Bv
    #pragma unroll
    for (int j = 0; j < E_; ++j) aemo[j] = 0.f;
    #pragma unroll
    for (int k = 0; k < 24; ++k) ag[k] = 0.f;

    #pragma unroll
    for (int i = 0; i < 3; ++i) {
        int d = i * 256 + lane * 4;           // 4 consecutive dims per lane
        float4 xv = *(const float4*)(x + d);
        float xr[4] = {xv.x, xv.y, xv.z, xv.w};

        // emoW rows d..d+3: 28 consecutive floats, 16B-aligned (28d bytes*4)
        float ewf[28];
        const float* ew = emoW + d * E_;
        #pragma unroll
        for (int q = 0; q < 7; ++q) {
            float4 t = *(const float4*)(ew + q * 4);
            ewf[q * 4 + 0] = t.x; ewf[q * 4 + 1] = t.y;
            ewf[q * 4 + 2] = t.z; ewf[q * 4 + 3] = t.w;
        }
        #pragma unroll
        for (int r = 0; r < 4; ++r)
            #pragma unroll
            for (int j = 0; j < E_; ++j) aemo[j] += xr[r] * ewf[r * 7 + j];

        // gate halves: rows d..d+3 -> 16 floats each half
        float gl[16], gh[16];
        const float* glp = gateW + d * NE_;
        const float* ghp = gateW + (HALF_ + d) * NE_;
        #pragma unroll
        for (int q = 0; q < 4; ++q) {
            float4 t0 = *(const float4*)(glp + q * 4);
            gl[q * 4 + 0] = t0.x; gl[q * 4 + 1] = t0.y;
            gl[q * 4 + 2] = t0.z; gl[q * 4 + 3] = t0.w;
            float4 t1 = *(const float4*)(ghp + q * 4);
            gh[q * 4 + 0] = t1.x; gh[q * 4 + 1] = t1.y;
            gh[q * 4 + 2] = t1.z; gh[q * 4 + 3] = t1.w;
        }
        #pragma unroll
        for (int r = 0; r < 4; ++r)
            #pragma unroll
            for (int k = 0; k < NE_; ++k) {
                ag[k]     += xr[r] * gl[r * 4 + k];
                ag[4 + k] += xr[r] * gh[r * 4 + k];
            }

        // W_eff halves: rows d..d+3 -> 32 floats each half
        float wl[32], wh[32];
        const float* wlp = ws + WEFF_OFF + d * 8;
        const float* whp = ws + WEFF_OFF + (HALF_ + d) * 8;
        #pragma unroll
        for (int q = 0; q < 8; ++q) {
            float4 t0 = *(const float4*)(wlp + q * 4);
            wl[q * 4 + 0] = t0.x; wl[q * 4 + 1] = t0.y;
            wl[q * 4 + 2] = t0.z; wl[q * 4 + 3] = t0.w;
            float4 t1 = *(const float4*)(whp + q * 4);
            wh[q * 4 + 0] = t1.x; wh[q * 4 + 1] = t1.y;
            wh[q * 4 + 2] = t1.z; wh[q * 4 + 3] = t1.w;
        }
        #pragma unroll
        for (int r = 0; r < 4; ++r)
            #pragma unroll
            for (int k = 0; k < 8; ++k) {
                ag[8 + k]  += xr[r] * wl[r * 8 + k];
                ag[16 + k] += xr[r] * wh[r * 8 + k];
            }
    }

    // reduce emotion sums across the wave (xor butterfly -> all lanes hold total)
    #pragma unroll
    for (int j = 0; j < E_; ++j) {
        float v = aemo[j];
        for (int o = 32; o > 0; o >>= 1) v += __shfl_xor(v, o, 64);
        aemo[j] = v + emoB[j];
    }

    if (lane == 0) {
        int best = 0; float bv = aemo[0];
        #pragma unroll
        for (int j = 1; j < E_; ++j) if (aemo[j] > bv) { bv = aemo[j]; best = j; }
        ((int*)ws)[EARG_OFF + row] = best;
        #pragma unroll
        for (int j = 0; j < E_; ++j) out[row * E_ + j] = aemo[j];
    }

    // tail dims 768..775: 7 emotion preds + speaker scalar; lanes 0..7 take one each
    if (lane < 8) {
        float v = (lane < E_) ? aemo[lane] : (float)spk[row];
        int d = H_ + lane;
        const float* glp = gateW + d * NE_;
        const float* ghp = gateW + (HALF_ + d) * NE_;
        #pragma unroll
        for (int k = 0; k < NE_; ++k) { ag[k] += v * glp[k]; ag[4 + k] += v * ghp[k]; }
        const float* wlp = ws + WEFF_OFF + d * 8;
        const float* whp = ws + WEFF_OFF + (HALF_ + d) * 8;
        #pragma unroll
        for (int k = 0; k < 8; ++k) { ag[8 + k] += v * wlp[k]; ag[16 + k] += v * whp[k]; }
    }

    // reduce the 24 projection sums
    #pragma unroll
    for (int k = 0; k < 24; ++k) {
        float v = ag[k];
        for (int o = 32; o > 0; o >>= 1) v += __shfl_xor(v, o, 64);
        ag[k] = v;
    }

    if (lane == 0) {
        #pragma unroll
        for (int k = 0; k < NE_; ++k) {
            ws[GLO_OFF + row * 4 + k] = ag[k];
            ws[GHI_OFF + row * 4 + k] = ag[4 + k];
        }
        #pragma unroll
        for (int k = 0; k < 8; ++k) {
            ws[AA_OFF + row * 8 + k] = ag[8 + k];
            ws[BB_OFF + row * 8 + k] = ag[16 + k];
        }
    }
}

// ---------------------------------------------------------------------------
// K3: one block per (b, end); thread t computes pair (t, end) for t <= end.
// ---------------------------------------------------------------------------
__global__ __launch_bounds__(128)
void k_pair(const int* __restrict__ spk,
            const float* __restrict__ ws,
            const float* __restrict__ gate_b,   // [4]
            float* __restrict__ out) {
    int b   = blockIdx.x >> 7;
    int end = blockIdx.x & 127;
    int t   = threadIdx.x;
    if (t > end) return;

    int rt = b * L_ + t;
    int re = b * L_ + end;

    // uniform constants -> scalar regs
    float gb[4] = {gate_b[0], gate_b[1], gate_b[2], gate_b[3]};
    float be[8];
    {
        float4 b0 = *(const float4*)(ws + BEFF_OFF);
        float4 b1v = *(const float4*)(ws + BEFF_OFF + 4);
        be[0]=b0.x; be[1]=b0.y; be[2]=b0.z; be[3]=b0.w;
        be[4]=b1v.x; be[5]=b1v.y; be[6]=b1v.z; be[7]=b1v.w;
    }

    float4 glo = *(const float4*)(ws + GLO_OFF + rt * 4);
    float4 ghi = *(const float4*)(ws + GHI_OFF + re * 4);
    float lg[NE_] = {glo.x + ghi.x + gb[0], glo.y + ghi.y + gb[1],
                     glo.z + ghi.z + gb[2], glo.w + ghi.w + gb[3]};

    float m = fmaxf(fmaxf(lg[0], lg[1]), fmaxf(lg[2], lg[3]));
    float ex[NE_], s = 0.f;
    #pragma unroll
    for (int k = 0; k < NE_; ++k) { ex[k] = expf(lg[k] - m); s += ex[k]; }
    float inv = 0.4f / s;

    const int* earg = (const int*)ws + EARG_OFF;
    bool seq = (spk[rt] == spk[re]);
    bool eeq = (earg[rt] == earg[re]);
    int lbl = (seq && eeq) ? 0 : (seq ? 1 : (eeq ? 2 : 3));

    float A[8], Bv[8];
    {
        float4 a0 = *(const float4*)(ws + AA_OFF + rt * 8);
        float4 a1 = *(const float4*)(ws + AA_OFF + rt * 8 + 4);
        A[0]=a0.x; A[1]=a0.y; A[2]=a0.z; A[3]=a0.w;
        A[4]=a1.x; A[5]=a1.y; A[6]=a1.z; A[7]=a1.w;
        float4 v0 = *(const float4*)(ws + BB_OFF + re * 8);
        float4 v1 = *(const float4*)(ws + BB_OFF + re * 8 + 4);
        Bv[0]=v0.x; Bv[1]=v0.y; Bv[2]=v0.z; Bv[3]=v0.w;
        Bv[4]=v1.x; Bv[5]=v1.y; Bv[6]=v1.z; Bv[7]=v1.w;
    }

    float o0 = 0.f, o1 = 0.f;
    #pragma unroll
    for (int e = 0; e < NE_; ++e) {
        float g = ex[e] * inv + ((e == lbl) ? 0.6f : 0.f);
        o0 += g * (A[e * 2 + 0] + Bv[e * 2 + 0] + be[e * 2 + 0]);
        o1 += g * (A[e * 2 + 1] + Bv[e * 2 + 1] + be[e * 2 + 1]);
    }

    int p = ((end * (end + 1)) >> 1) + t;
    float* cp = out + EMO_OUT_ + ((size_t)b * PPB_ + p) * 2;
    cp[0] = o0;
    cp[1] = o1;
}

// ---------------------------------------------------------------------------
extern "C" void kernel_launch(void* const* d_in, const int* in_sizes, int n_in,
                              void* d_out, int out_size, void* d_ws, size_t ws_size,
                              hipStream_t stream) {
    const float* utter = (const float*)d_in[0];  // [8,128,768]
    const int*   spk   = (const int*)  d_in[1];  // [8,128]
    const float* emoW  = (const float*)d_in[2];  // [768,7]
    const float* emoB  = (const float*)d_in[3];  // [7]
    const float* gateW = (const float*)d_in[4];  // [1552,4]
    const float* gateB = (const float*)d_in[5];  // [4]
    const float* w1    = (const float*)d_in[6];  // [4,1552,256]
    const float* b1    = (const float*)d_in[7];  // [4,256]
    const float* w2    = (const float*)d_in[8];  // [4,256,2]
    const float* b2    = (const float*)d_in[9];  // [4,2]

    float* ws  = (float*)d_ws;
    float* out = (float*)d_out;

    // K1: effective expert weights (97 work blocks + 1 bias block)
    k_weff<<<WEFF_BLOCKS + 1, 256, 0, stream>>>(w1, w2, b1, b2, ws);
    // K2: per-utterance-row projections (one wave per row)
    k_row<<<NROW_, 64, 0, stream>>>(utter, spk, emoW, emoB, gateW, ws, out);
    // K3: per-pair gating + output (one block per (b, end))
    k_pair<<<B_ * L_, 128, 0, stream>>>(spk, ws, gateB, out);
}

// Round 5
// 92.732 us; speedup vs baseline: 1.1047x; 1.0277x over previous
//
#include <hip/hip_runtime.h>
#include <math.h>

// Problem constants (from reference setup_inputs)
#define B_   8
#define L_   128
#define H_   768
#define E_   7          // emotion classes
#define NE_  4          // experts
#define HALF_ 776       // H + E + 1
#define D_   1552       // 2*HALF
#define PPB_ 8256       // L*(L+1)/2
#define NROW_ 1024      // B*L
#define EMO_OUT_ 7168   // NROW_*E_  (emotion_pred floats at head of d_out)

// workspace layout (float units) -- all offsets 16B-aligned
#define WEFF_OFF 0          // [1552][4][2] = 12416  (d-major: d*8 + e*2 + c)
#define BEFF_OFF 12416      // [4][2] = 8
#define EARG_OFF 12424      // [1024] int (reinterpreted)
#define GLO_OFF  13448      // [1024][4]
#define GHI_OFF  17544      // [1024][4]
#define AA_OFF   21640      // [1024][4][2]
#define BB_OFF   29832      // [1024][4][2]

#define WEFF_BLOCKS 194     // 6208 (e,d) pairs / 32 per block

// ---------------------------------------------------------------------------
// K1: collapse each expert's two linears into W_eff[d][e][c], b_eff[e][c].
// 194 blocks x 256 threads: 32 (e,d) pairs per block, 8-way h-split + LDS
// reduce. Block 194 computes b_eff with one wave.
// ---------------------------------------------------------------------------
__global__ __launch_bounds__(256)
void k_weff(const float* __restrict__ w1,   // [4][1552][256]
            const float* __restrict__ w2,   // [4][256][2]
            const float* __restrict__ b1,   // [4][256]
            const float* __restrict__ b2,   // [4][2]
            float* __restrict__ ws) {
    int blk = blockIdx.x;
    if (blk < WEFF_BLOCKS) {
        __shared__ float red[8][32][2];
        int dl = threadIdx.x & 31;
        int hc = threadIdx.x >> 5;            // h-chunk 0..7 (32 h each)
        int idx = blk * 32 + dl;              // (e,d) flat index, < 6208
        int e = idx / D_, d = idx % D_;
        const float* w1row = w1 + ((size_t)e * D_ + d) * 256 + hc * 32;
        const float* w2e   = w2 + e * 512 + hc * 64;
        float a0 = 0.f, a1 = 0.f;
        #pragma unroll
        for (int h = 0; h < 32; h += 4) {
            float4 wv = *(const float4*)(w1row + h);
            float4 p0 = *(const float4*)(w2e + 2 * h);      // rows h, h+1
            float4 p1 = *(const float4*)(w2e + 2 * h + 4);  // rows h+2, h+3
            a0 += wv.x * p0.x + wv.y * p0.z + wv.z * p1.x + wv.w * p1.z;
            a1 += wv.x * p0.y + wv.y * p0.w + wv.z * p1.y + wv.w * p1.w;
        }
        red[hc][dl][0] = a0;
        red[hc][dl][1] = a1;
        __syncthreads();
        if (hc == 0) {
            float s0 = 0.f, s1 = 0.f;
            #pragma unroll
            for (int q = 0; q < 8; ++q) { s0 += red[q][dl][0]; s1 += red[q][dl][1]; }
            ws[WEFF_OFF + d * 8 + e * 2 + 0] = s0;
            ws[WEFF_OFF + d * 8 + e * 2 + 1] = s1;
        }
    } else {
        // b_eff[e][c] = b2[e][c] + sum_h b1[e][h] * W2[e][h][c]
        int lane = threadIdx.x;
        if (lane < 64) {
            int j = lane >> 3;                // output 0..7 (e*2+c)
            int part = lane & 7;              // 8-way h split
            int e = j >> 1, c = j & 1;
            const float* w2e = w2 + e * 512;
            const float* b1e = b1 + e * 256;
            float acc = 0.f;
            #pragma unroll 8
            for (int h = part * 32; h < part * 32 + 32; ++h)
                acc += b1e[h] * w2e[2 * h + c];
            acc += __shfl_down(acc, 4, 64);
            acc += __shfl_down(acc, 2, 64);
            acc += __shfl_down(acc, 1, 64);
            if (part == 0) ws[BEFF_OFF + j] = acc + b2[j];
        }
    }
}

// ---------------------------------------------------------------------------
// K2: 3 waves (192 threads) per utterance row; wave w covers dims
// [w*256, w*256+256), each lane 4 consecutive dims via float4 (1 iteration).
// Cross-wave combine via LDS; wave 0 handles tail dims + stores.
// ---------------------------------------------------------------------------
__global__ __launch_bounds__(192)
void k_row(const float* __restrict__ utter,   // [1024][768]
           const int*   __restrict__ spk,     // [1024]
           const float* __restrict__ emoW,    // [768][7]
           const float* __restrict__ emoB,    // [7]
           const float* __restrict__ gateW,   // [1552][4]
           float* __restrict__ ws,
           float* __restrict__ out) {
    int row  = blockIdx.x;
    int wv   = threadIdx.x >> 6;              // wave 0..2
    int lane = threadIdx.x & 63;
    const float* x = utter + (size_t)row * H_;

    float aemo[E_];
    float ag[24];   // [0..3]=G_lo  [4..7]=G_hi  [8..15]=A  [16..23]=Bv
    #pragma unroll
    for (int j = 0; j < E_; ++j) aemo[j] = 0.f;
    #pragma unroll
    for (int k = 0; k < 24; ++k) ag[k] = 0.f;

    int d = wv * 256 + lane * 4;              // 4 consecutive dims, one shot
    float4 xv = *(const float4*)(x + d);
    float xr[4] = {xv.x, xv.y, xv.z, xv.w};

    // emoW rows d..d+3: 28 consecutive floats, 16B-aligned
    float ewf[28];
    const float* ew = emoW + d * E_;
    #pragma unroll
    for (int q = 0; q < 7; ++q) {
        float4 t = *(const float4*)(ew + q * 4);
        ewf[q * 4 + 0] = t.x; ewf[q * 4 + 1] = t.y;
        ewf[q * 4 + 2] = t.z; ewf[q * 4 + 3] = t.w;
    }
    #pragma unroll
    for (int r = 0; r < 4; ++r)
        #pragma unroll
        for (int j = 0; j < E_; ++j) aemo[j] += xr[r] * ewf[r * 7 + j];

    // gate halves: rows d..d+3 -> 16 floats each half
    float gl[16], gh[16];
    const float* glp = gateW + d * NE_;
    const float* ghp = gateW + (HALF_ + d) * NE_;
    #pragma unroll
    for (int q = 0; q < 4; ++q) {
        float4 t0 = *(const float4*)(glp + q * 4);
        gl[q * 4 + 0] = t0.x; gl[q * 4 + 1] = t0.y;
        gl[q * 4 + 2] = t0.z; gl[q * 4 + 3] = t0.w;
        float4 t1 = *(const float4*)(ghp + q * 4);
        gh[q * 4 + 0] = t1.x; gh[q * 4 + 1] = t1.y;
        gh[q * 4 + 2] = t1.z; gh[q * 4 + 3] = t1.w;
    }
    #pragma unroll
    for (int r = 0; r < 4; ++r)
        #pragma unroll
        for (int k = 0; k < NE_; ++k) {
            ag[k]     += xr[r] * gl[r * 4 + k];
            ag[4 + k] += xr[r] * gh[r * 4 + k];
        }

    // W_eff halves: rows d..d+3 -> 32 floats each half
    float wl[32], wh[32];
    const float* wlp = ws + WEFF_OFF + d * 8;
    const float* whp = ws + WEFF_OFF + (HALF_ + d) * 8;
    #pragma unroll
    for (int q = 0; q < 8; ++q) {
        float4 t0 = *(const float4*)(wlp + q * 4);
        wl[q * 4 + 0] = t0.x; wl[q * 4 + 1] = t0.y;
        wl[q * 4 + 2] = t0.z; wl[q * 4 + 3] = t0.w;
        float4 t1 = *(const float4*)(whp + q * 4);
        wh[q * 4 + 0] = t1.x; wh[q * 4 + 1] = t1.y;
        wh[q * 4 + 2] = t1.z; wh[q * 4 + 3] = t1.w;
    }
    #pragma unroll
    for (int r = 0; r < 4; ++r)
        #pragma unroll
        for (int k = 0; k < 8; ++k) {
            ag[8 + k]  += xr[r] * wl[r * 8 + k];
            ag[16 + k] += xr[r] * wh[r * 8 + k];
        }

    // in-wave butterfly: lane 0 of each wave holds wave totals
    #pragma unroll
    for (int j = 0; j < E_; ++j) {
        float v = aemo[j];
        for (int o = 32; o > 0; o >>= 1) v += __shfl_xor(v, o, 64);
        aemo[j] = v;
    }
    #pragma unroll
    for (int k = 0; k < 24; ++k) {
        float v = ag[k];
        for (int o = 32; o > 0; o >>= 1) v += __shfl_xor(v, o, 64);
        ag[k] = v;
    }

    __shared__ float red[3][31];
    if (lane == 0) {
        #pragma unroll
        for (int j = 0; j < E_; ++j) red[wv][j] = aemo[j];
        #pragma unroll
        for (int k = 0; k < 24; ++k) red[wv][E_ + k] = ag[k];
    }
    __syncthreads();

    if (wv == 0) {
        float tot[31];
        #pragma unroll
        for (int k = 0; k < 31; ++k) tot[k] = red[0][k] + red[1][k] + red[2][k];
        float aem[E_];
        #pragma unroll
        for (int j = 0; j < E_; ++j) aem[j] = tot[j] + emoB[j];

        if (lane == 0) {
            int best = 0; float bv = aem[0];
            #pragma unroll
            for (int j = 1; j < E_; ++j) if (aem[j] > bv) { bv = aem[j]; best = j; }
            ((int*)ws)[EARG_OFF + row] = best;
            #pragma unroll
            for (int j = 0; j < E_; ++j) out[row * E_ + j] = aem[j];
        }

        // tail dims 768..775: 7 emotion preds + speaker; lanes 0..7 one each
        float tail[24];
        #pragma unroll
        for (int k = 0; k < 24; ++k) tail[k] = 0.f;
        if (lane < 8) {
            float v = (lane < E_) ? aem[lane] : (float)spk[row];
            int dd = H_ + lane;
            const float* tgl = gateW + dd * NE_;
            const float* tgh = gateW + (HALF_ + dd) * NE_;
            #pragma unroll
            for (int k = 0; k < NE_; ++k) { tail[k] = v * tgl[k]; tail[4 + k] = v * tgh[k]; }
            const float* twl = ws + WEFF_OFF + dd * 8;
            const float* twh = ws + WEFF_OFF + (HALF_ + dd) * 8;
            #pragma unroll
            for (int k = 0; k < 8; ++k) { tail[8 + k] = v * twl[k]; tail[16 + k] = v * twh[k]; }
            // reduce across the 8 lanes
            #pragma unroll
            for (int k = 0; k < 24; ++k) {
                float t = tail[k];
                t += __shfl_xor(t, 4, 8);
                t += __shfl_xor(t, 2, 8);
                t += __shfl_xor(t, 1, 8);
                tail[k] = t;
            }
        }

        if (lane == 0) {
            #pragma unroll
            for (int k = 0; k < NE_; ++k) {
                ws[GLO_OFF + row * 4 + k] = tot[E_ + k] + tail[k];
                ws[GHI_OFF + row * 4 + k] = tot[E_ + 4 + k] + tail[4 + k];
            }
            #pragma unroll
            for (int k = 0; k < 8; ++k) {
                ws[AA_OFF + row * 8 + k] = tot[E_ + 8 + k] + tail[8 + k];
                ws[BB_OFF + row * 8 + k] = tot[E_ + 16 + k] + tail[16 + k];
            }
        }
    }
}

// ---------------------------------------------------------------------------
// K3: flat over all 66048 pairs, one per thread (triangular decode).
// ---------------------------------------------------------------------------
__global__ __launch_bounds__(256)
void k_pair(const int* __restrict__ spk,
            const float* __restrict__ ws,
            const float* __restrict__ gate_b,   // [4]
            float* __restrict__ out) {
    int tid = blockIdx.x * 256 + threadIdx.x;   // < 66048 exactly (258*256)
    int b = tid / PPB_;
    int p = tid - b * PPB_;
    // decode p -> (end, t): p = end*(end+1)/2 + t, 0 <= t <= end
    int e = (int)((sqrtf(8.f * (float)p + 1.f) - 1.f) * 0.5f);
    while ((e + 1) * (e + 2) / 2 <= p) ++e;
    while (e * (e + 1) / 2 > p) --e;
    int t = p - e * (e + 1) / 2;

    int rt = b * L_ + t;
    int re = b * L_ + e;

    // uniform constants -> scalar regs
    float gb[4] = {gate_b[0], gate_b[1], gate_b[2], gate_b[3]};
    float be[8];
    {
        float4 b0 = *(const float4*)(ws + BEFF_OFF);
        float4 b1v = *(const float4*)(ws + BEFF_OFF + 4);
        be[0]=b0.x; be[1]=b0.y; be[2]=b0.z; be[3]=b0.w;
        be[4]=b1v.x; be[5]=b1v.y; be[6]=b1v.z; be[7]=b1v.w;
    }

    float4 glo = *(const float4*)(ws + GLO_OFF + rt * 4);
    float4 ghi = *(const float4*)(ws + GHI_OFF + re * 4);
    float lg[NE_] = {glo.x + ghi.x + gb[0], glo.y + ghi.y + gb[1],
                     glo.z + ghi.z + gb[2], glo.w + ghi.w + gb[3]};

    float m = fmaxf(fmaxf(lg[0], lg[1]), fmaxf(lg[2], lg[3]));
    float ex[NE_], s = 0.f;
    #pragma unroll
    for (int k = 0; k < NE_; ++k) { ex[k] = expf(lg[k] - m); s += ex[k]; }
    float inv = 0.4f / s;

    const int* earg = (const int*)ws + EARG_OFF;
    bool seq = (spk[rt] == spk[re]);
    bool eeq = (earg[rt] == earg[re]);
    int lbl = (seq && eeq) ? 0 : (seq ? 1 : (eeq ? 2 : 3));

    float A[8], Bv[8];
    {
        float4 a0 = *(const float4*)(ws + AA_OFF + rt * 8);
        float4 a1 = *(const float4*)(ws + AA_OFF + rt * 8 + 4);
        A[0]=a0.x; A[1]=a0.y; A[2]=a0.z; A[3]=a0.w;
        A[4]=a1.x; A[5]=a1.y; A[6]=a1.z; A[7]=a1.w;
        float4 v0 = *(const float4*)(ws + BB_OFF + re * 8);
        float4 v1 = *(const float4*)(ws + BB_OFF + re * 8 + 4);
        Bv[0]=v0.x; Bv[1]=v0.y; Bv[2]=v0.z; Bv[3]=v0.w;
        Bv[4]=v1.x; Bv[5]=v1.y; Bv[6]=v1.z; Bv[7]=v1.w;
    }

    float o0 = 0.f, o1 = 0.f;
    #pragma unroll
    for (int ee = 0; ee < NE_; ++ee) {
        float g = ex[ee] * inv + ((ee == lbl) ? 0.6f : 0.f);
        o0 += g * (A[ee * 2 + 0] + Bv[ee * 2 + 0] + be[ee * 2 + 0]);
        o1 += g * (A[ee * 2 + 1] + Bv[ee * 2 + 1] + be[ee * 2 + 1]);
    }

    float* cp = out + EMO_OUT_ + ((size_t)b * PPB_ + p) * 2;
    cp[0] = o0;
    cp[1] = o1;
}

// ---------------------------------------------------------------------------
extern "C" void kernel_launch(void* const* d_in, const int* in_sizes, int n_in,
                              void* d_out, int out_size, void* d_ws, size_t ws_size,
                              hipStream_t stream) {
    const float* utter = (const float*)d_in[0];  // [8,128,768]
    const int*   spk   = (const int*)  d_in[1];  // [8,128]
    const float* emoW  = (const float*)d_in[2];  // [768,7]
    const float* emoB  = (const float*)d_in[3];  // [7]
    const float* gateW = (const float*)d_in[4];  // [1552,4]
    const float* gateB = (const float*)d_in[5];  // [4]
    const float* w1    = (const float*)d_in[6];  // [4,1552,256]
    const float* b1    = (const float*)d_in[7];  // [4,256]
    const float* w2    = (const float*)d_in[8];  // [4,256,2]
    const float* b2    = (const float*)d_in[9];  // [4,2]

    float* ws  = (float*)d_ws;
    float* out = (float*)d_out;

    // K1: effective expert weights (194 work blocks + 1 bias block)
    k_weff<<<WEFF_BLOCKS + 1, 256, 0, stream>>>(w1, w2, b1, b2, ws);
    // K2: per-utterance-row projections (3 waves per row)
    k_row<<<NROW_, 192, 0, stream>>>(utter, spk, emoW, emoB, gateW, ws, out);
    // K3: per-pair gating + output (one thread per pair, 258*256 = 66048)
    k_pair<<<258, 256, 0, stream>>>(spk, ws, gateB, out);
}